// Round 1
// baseline (1171.254 us; speedup 1.0000x reference)
//
#include <hip/hip_runtime.h>

constexpr int NB   = 64;                 // graphs per batch
constexpr int NPG  = 1024;               // nodes per graph
constexpr int EPG  = 16384;              // edges per graph
constexpr int NTOT = NB * NPG;           // 65536 nodes
constexpr int ETOT = NB * EPG;           // 1048576 edges
constexpr int FIN  = 64;
constexpr int FHID = 128;
constexpr int FOUT = 32;

// ---------------------------------------------------------------- degrees
__global__ void k_deg(const int* __restrict__ src, const int* __restrict__ dst,
                      int* __restrict__ dego, int* __restrict__ degi) {
  int i = blockIdx.x * blockDim.x + threadIdx.x;
  if (i < ETOT) {
    atomicAdd(&dego[src[i]], 1);
    atomicAdd(&degi[dst[i]], 1);
  }
}

__global__ void k_scales(const int* __restrict__ dego, const int* __restrict__ degi,
                         float* __restrict__ rso, float* __restrict__ rsi) {
  int i = blockIdx.x * blockDim.x + threadIdx.x;
  if (i < NTOT) {
    int a = dego[i] > 1 ? dego[i] : 1;
    int b = degi[i] > 1 ? degi[i] : 1;
    rso[i] = rsqrtf((float)a);
    rsi[i] = rsqrtf((float)b);
  }
}

// ------------------------------------------------- LDS-accumulated scatter
// One block per (graph, 16-dim slice). LDS accumulator 1024 nodes x 16 dims
// = 64 KB. ds_add_f32 atomics: lanes = 4 edges x 16 dims -> ~2-way bank
// aliasing (free). rs != nullptr applies per-source scaling (layer 1).
__global__ __launch_bounds__(1024) void k_agg(
    const int* __restrict__ src, const int* __restrict__ dst,
    const float* __restrict__ x, const float* __restrict__ rs,
    float* __restrict__ out) {
  __shared__ float acc[NPG * 16];
  const int g  = blockIdx.x;
  const int d0 = blockIdx.y * 16;
  for (int i = threadIdx.x; i < NPG * 16; i += 1024) acc[i] = 0.0f;
  __syncthreads();
  const int dim  = threadIdx.x & 15;
  const int slot = threadIdx.x >> 4;     // 64 edge slots
  const int gb   = g * NPG;
  const int eb   = g * EPG;
  for (int e = slot; e < EPG; e += 64) {
    int s = src[eb + e];
    int d = dst[eb + e];
    float v = x[(size_t)s * FIN + d0 + dim];
    if (rs) v *= rs[s];
    atomicAdd(&acc[(d - gb) * 16 + dim], v);
  }
  __syncthreads();
  for (int i = threadIdx.x; i < NPG * 4; i += 1024) {
    int node = i >> 2, dq = i & 3;
    *(float4*)&out[(size_t)(gb + node) * FIN + d0 + dq * 4] =
        *(float4*)&acc[node * 16 + dq * 4];
  }
}

// ------------------------------------------------- GEMM1: h = relu((m1*rs_in)@W1 + b1) * rs_out
// tile: 64 nodes x 128 hid, k=64. 256 threads, 4 nodes x 8 dims each.
__global__ __launch_bounds__(256) void k_gemm1(
    const float* __restrict__ m1, const float* __restrict__ rsi,
    const float* __restrict__ rso, const float* __restrict__ W1,
    const float* __restrict__ b1, float* __restrict__ h) {
  __shared__ float sA[FIN][64];          // [k][node], 16 KB
  __shared__ float sW[FIN * FHID];       // [k][j],    32 KB
  __shared__ float sB[FHID];
  const int t = threadIdx.x;
  const int node0 = blockIdx.x * 64;
  for (int f = t; f < FIN * FHID / 4; f += 256)
    ((float4*)sW)[f] = ((const float4*)W1)[f];
  if (t < FHID) sB[t] = b1[t];
  // transposed A staging with rs_in fold; lanes: node = f&63 -> 2-way free writes
  for (int f = t; f < 64 * (FIN / 4); f += 256) {
    int node = f & 63, kq = f >> 6;
    float sc = rsi[node0 + node];
    float4 v = *(const float4*)&m1[(size_t)(node0 + node) * FIN + kq * 4];
    sA[kq * 4 + 0][node] = v.x * sc;
    sA[kq * 4 + 1][node] = v.y * sc;
    sA[kq * 4 + 2][node] = v.z * sc;
    sA[kq * 4 + 3][node] = v.w * sc;
  }
  __syncthreads();
  const int tx = t & 15, ty = t >> 4;    // j0 = tx*8, n0 = ty*4
  float acc[4][8];
#pragma unroll
  for (int r = 0; r < 4; ++r)
#pragma unroll
    for (int c = 0; c < 8; ++c) acc[r][c] = 0.0f;
#pragma unroll 4
  for (int k = 0; k < FIN; ++k) {
    float4 a  = *(float4*)&sA[k][ty * 4];
    float4 w0 = *(float4*)&sW[k * FHID + tx * 8];
    float4 w1 = *(float4*)&sW[k * FHID + tx * 8 + 4];
    float av[4] = {a.x, a.y, a.z, a.w};
    float wv[8] = {w0.x, w0.y, w0.z, w0.w, w1.x, w1.y, w1.z, w1.w};
#pragma unroll
    for (int r = 0; r < 4; ++r)
#pragma unroll
      for (int c = 0; c < 8; ++c) acc[r][c] = fmaf(av[r], wv[c], acc[r][c]);
  }
#pragma unroll
  for (int r = 0; r < 4; ++r) {
    int node = node0 + ty * 4 + r;
    float sc = rso[node];
    float4 o0, o1;
    o0.x = fmaxf(acc[r][0] + sB[tx * 8 + 0], 0.f) * sc;
    o0.y = fmaxf(acc[r][1] + sB[tx * 8 + 1], 0.f) * sc;
    o0.z = fmaxf(acc[r][2] + sB[tx * 8 + 2], 0.f) * sc;
    o0.w = fmaxf(acc[r][3] + sB[tx * 8 + 3], 0.f) * sc;
    o1.x = fmaxf(acc[r][4] + sB[tx * 8 + 4], 0.f) * sc;
    o1.y = fmaxf(acc[r][5] + sB[tx * 8 + 5], 0.f) * sc;
    o1.z = fmaxf(acc[r][6] + sB[tx * 8 + 6], 0.f) * sc;
    o1.w = fmaxf(acc[r][7] + sB[tx * 8 + 7], 0.f) * sc;
    *(float4*)&h[(size_t)node * FHID + tx * 8]     = o0;
    *(float4*)&h[(size_t)node * FHID + tx * 8 + 4] = o1;
  }
}

// ------------------------------------------------- GEMM2: p = h @ [W2 | W3]
// tile: 64 nodes x 64 out, k=128. 256 threads, 4x4 each.
__global__ __launch_bounds__(256) void k_gemm2(
    const float* __restrict__ h, const float* __restrict__ W2,
    const float* __restrict__ W3, float* __restrict__ p) {
  __shared__ float sA[FHID][64];         // [k][node], 32 KB
  __shared__ float sW[FHID * 64];        // [k][j], j<32 -> W2, else W3, 32 KB
  const int t = threadIdx.x;
  const int node0 = blockIdx.x * 64;
  for (int f = t; f < FHID * FOUT / 4; f += 256) {
    int k = f >> 3, jq = f & 7;
    *(float4*)&sW[k * 64 + jq * 4]      = *(const float4*)&W2[k * FOUT + jq * 4];
  }
  for (int f = t; f < FHID * FOUT / 4; f += 256) {
    int k = f >> 3, jq = f & 7;
    *(float4*)&sW[k * 64 + 32 + jq * 4] = *(const float4*)&W3[k * FOUT + jq * 4];
  }
  for (int f = t; f < 64 * (FHID / 4); f += 256) {
    int node = f & 63, kq = f >> 6;
    float4 v = *(const float4*)&h[(size_t)(node0 + node) * FHID + kq * 4];
    sA[kq * 4 + 0][node] = v.x;
    sA[kq * 4 + 1][node] = v.y;
    sA[kq * 4 + 2][node] = v.z;
    sA[kq * 4 + 3][node] = v.w;
  }
  __syncthreads();
  const int tx = t & 15, ty = t >> 4;    // j0 = tx*4, n0 = ty*4
  float acc[4][4];
#pragma unroll
  for (int r = 0; r < 4; ++r)
#pragma unroll
    for (int c = 0; c < 4; ++c) acc[r][c] = 0.0f;
#pragma unroll 4
  for (int k = 0; k < FHID; ++k) {
    float4 a = *(float4*)&sA[k][ty * 4];
    float4 w = *(float4*)&sW[k * 64 + tx * 4];
    float av[4] = {a.x, a.y, a.z, a.w};
    float wv[4] = {w.x, w.y, w.z, w.w};
#pragma unroll
    for (int r = 0; r < 4; ++r)
#pragma unroll
      for (int c = 0; c < 4; ++c) acc[r][c] = fmaf(av[r], wv[c], acc[r][c]);
  }
#pragma unroll
  for (int r = 0; r < 4; ++r) {
    float4 o = {acc[r][0], acc[r][1], acc[r][2], acc[r][3]};
    *(float4*)&p[(size_t)(node0 + ty * 4 + r) * 64 + tx * 4] = o;
  }
}

// ------------------------------------------------- epilogue: mean / log_std
__global__ void k_epi(const float* __restrict__ m2, const float* __restrict__ rsi,
                      const float* __restrict__ b2, const float* __restrict__ b3,
                      float* __restrict__ mean_, float* __restrict__ logstd_) {
  int t = blockIdx.x * blockDim.x + threadIdx.x;   // NTOT*8 threads
  int node = t >> 3, q = t & 7;                    // 8 quads of 4 dims
  float ri = rsi[node];
  float4 mm = *(const float4*)&m2[(size_t)node * 64 + q * 4];
  float4 ll = *(const float4*)&m2[(size_t)node * 64 + 32 + q * 4];
  float4 bb2 = *(const float4*)&b2[q * 4];
  float4 bb3 = *(const float4*)&b3[q * 4];
  float4 me = {mm.x * ri + bb2.x, mm.y * ri + bb2.y, mm.z * ri + bb2.z, mm.w * ri + bb2.w};
  float4 ls = {ll.x * ri + bb3.x, ll.y * ri + bb3.y, ll.z * ri + bb3.z, ll.w * ri + bb3.w};
  *(float4*)&mean_[(size_t)node * FOUT + q * 4]   = me;
  *(float4*)&logstd_[(size_t)node * FOUT + q * 4] = ls;
}

// ------------------------------------------------- adj = sigmoid(z z^T) per graph
// z recomputed from mean/log_std/noise during staging (no z buffer -> no
// read/write hazard with the adj region). 128x128 tile, 8x8 per thread.
__global__ __launch_bounds__(256) void k_adj(
    const float* __restrict__ mean_, const float* __restrict__ logstd_,
    const float* __restrict__ noise, float* __restrict__ adj) {
  __shared__ float sR[FOUT][128];        // [k][row], 16 KB
  __shared__ float sC[FOUT][128];        // [k][col], 16 KB
  const int g  = blockIdx.z;
  const int c0 = blockIdx.x * 128;
  const int r0 = blockIdx.y * 128;
  const int t  = threadIdx.x;
  const size_t gb = (size_t)g * NPG;
  for (int f = t; f < 2048; f += 256) {
    int half = f >> 10;
    int ff   = f & 1023;
    int node = ff & 127, kq = ff >> 7;   // kq 0..7
    int base = half ? c0 : r0;
    size_t idx = (gb + base + node) * FOUT + kq * 4;
    float4 m  = *(const float4*)&mean_[idx];
    float4 l  = *(const float4*)&logstd_[idx];
    float4 nz = *(const float4*)&noise[idx];
    float* s = half ? &sC[0][0] : &sR[0][0];
    s[(kq * 4 + 0) * 128 + node] = m.x + nz.x * __expf(l.x);
    s[(kq * 4 + 1) * 128 + node] = m.y + nz.y * __expf(l.y);
    s[(kq * 4 + 2) * 128 + node] = m.z + nz.z * __expf(l.z);
    s[(kq * 4 + 3) * 128 + node] = m.w + nz.w * __expf(l.w);
  }
  __syncthreads();
  const int tx = t & 15, ty = t >> 4;    // col chunk tx*8, row chunk ty*8
  float acc[8][8];
#pragma unroll
  for (int r = 0; r < 8; ++r)
#pragma unroll
    for (int c = 0; c < 8; ++c) acc[r][c] = 0.0f;
#pragma unroll 2
  for (int k = 0; k < FOUT; ++k) {
    float ar[8], ac[8];
    *(float4*)&ar[0] = *(float4*)&sR[k][ty * 8];
    *(float4*)&ar[4] = *(float4*)&sR[k][ty * 8 + 4];
    *(float4*)&ac[0] = *(float4*)&sC[k][tx * 8];
    *(float4*)&ac[4] = *(float4*)&sC[k][tx * 8 + 4];
#pragma unroll
    for (int r = 0; r < 8; ++r)
#pragma unroll
      for (int c = 0; c < 8; ++c) acc[r][c] = fmaf(ar[r], ac[c], acc[r][c]);
  }
#pragma unroll
  for (int r = 0; r < 8; ++r) {
    size_t o = (gb + r0 + ty * 8 + r) * (size_t)NPG + c0 + tx * 8;
    float4 s0, s1;
    s0.x = 1.0f / (1.0f + __expf(-acc[r][0]));
    s0.y = 1.0f / (1.0f + __expf(-acc[r][1]));
    s0.z = 1.0f / (1.0f + __expf(-acc[r][2]));
    s0.w = 1.0f / (1.0f + __expf(-acc[r][3]));
    s1.x = 1.0f / (1.0f + __expf(-acc[r][4]));
    s1.y = 1.0f / (1.0f + __expf(-acc[r][5]));
    s1.z = 1.0f / (1.0f + __expf(-acc[r][6]));
    s1.w = 1.0f / (1.0f + __expf(-acc[r][7]));
    *(float4*)&adj[o]     = s0;
    *(float4*)&adj[o + 4] = s1;
  }
}

extern "C" void kernel_launch(void* const* d_in, const int* in_sizes, int n_in,
                              void* d_out, int out_size, void* d_ws, size_t ws_size,
                              hipStream_t stream) {
  const float* features = (const float*)d_in[0];   // N x 64
  const int*   src      = (const int*)d_in[1];     // E
  const int*   dst      = (const int*)d_in[2];     // E
  const float* noise    = (const float*)d_in[3];   // N x 32
  const float* W1       = (const float*)d_in[4];   // 64 x 128
  const float* b1       = (const float*)d_in[5];   // 128
  const float* W2       = (const float*)d_in[6];   // 128 x 32
  const float* b2       = (const float*)d_in[7];   // 32
  const float* W3       = (const float*)d_in[8];   // 128 x 32
  const float* b3       = (const float*)d_in[9];   // 32

  float* adj     = (float*)d_out;                              // 64*1024*1024
  float* mean_   = adj + (size_t)NB * NPG * NPG;               // N*32
  float* logstd_ = mean_ + (size_t)NTOT * FOUT;                // N*32

  // Scratch lives inside the adj region (written only by the final kernel,
  // which reads nothing from it). ~85 MB of 268 MB used. No ws dependence.
  int*   dego = (int*)adj;                       // N ints
  int*   degi = dego + NTOT;                     // N ints
  float* rso  = (float*)(degi + NTOT);           // N
  float* rsi  = rso + NTOT;                      // N
  float* m1   = rsi + NTOT;                      // N*64
  float* m2   = m1 + (size_t)NTOT * FIN;         // N*64
  float* h    = m2 + (size_t)NTOT * FIN;         // N*128
  float* p    = h + (size_t)NTOT * FHID;         // N*64

  hipMemsetAsync(dego, 0, (size_t)2 * NTOT * sizeof(int), stream);
  k_deg<<<ETOT / 256, 256, 0, stream>>>(src, dst, dego, degi);
  k_scales<<<NTOT / 256, 256, 0, stream>>>(dego, degi, rso, rsi);
  // layer 1 aggregate: m1 = Agg(features * rs_out[src])
  k_agg<<<dim3(NB, FIN / 16), 1024, 0, stream>>>(src, dst, features, rso, m1);
  // h = relu((m1 * rs_in) @ W1 + b1) * rs_out   (rs_out folded for layer 2)
  k_gemm1<<<NTOT / 64, 256, 0, stream>>>(m1, rsi, rso, W1, b1, h);
  // p = h @ [W2 | W3]  (project BEFORE aggregating: halves scatter traffic)
  k_gemm2<<<NTOT / 64, 256, 0, stream>>>(h, W2, W3, p);
  // layer 2 aggregate: m2 = Agg(p)
  k_agg<<<dim3(NB, FIN / 16), 1024, 0, stream>>>(src, dst, p, nullptr, m2);
  // mean = m2[:, :32]*rs_in + b2 ; log_std = m2[:, 32:]*rs_in + b3
  k_epi<<<NTOT * 8 / 256, 256, 0, stream>>>(m2, rsi, b2, b3, mean_, logstd_);
  // adj = sigmoid(z z^T), z recomputed in-kernel
  k_adj<<<dim3(NPG / 128, NPG / 128, NB), 256, 0, stream>>>(mean_, logstd_, noise, adj);
}

// Round 2
// 1128.132 us; speedup vs baseline: 1.0382x; 1.0382x over previous
//
#include <hip/hip_runtime.h>

constexpr int NB   = 64;                 // graphs per batch
constexpr int NPG  = 1024;               // nodes per graph
constexpr int EPG  = 16384;              // edges per graph
constexpr int NTOT = NB * NPG;           // 65536 nodes
constexpr int ETOT = NB * EPG;           // 1048576 edges
constexpr int FIN  = 64;
constexpr int FHID = 128;
constexpr int FOUT = 32;

// ------------------------------------------------- degrees via LDS histogram
// grid (NB, 4): each block histograms 4096 edges of one graph in LDS, then
// merges with global atomics (2048 ints per block, ~no contention).
__global__ __launch_bounds__(1024) void k_deg(
    const int* __restrict__ src, const int* __restrict__ dst,
    int* __restrict__ dego, int* __restrict__ degi) {
  __shared__ int so[NPG], si[NPG];
  const int g = blockIdx.x, q = blockIdx.y;
  for (int i = threadIdx.x; i < NPG; i += 1024) { so[i] = 0; si[i] = 0; }
  __syncthreads();
  const int eb = g * EPG + q * (EPG / 4);
  const int gb = g * NPG;
  for (int e = threadIdx.x; e < EPG / 4; e += 1024) {
    atomicAdd(&so[src[eb + e] - gb], 1);
    atomicAdd(&si[dst[eb + e] - gb], 1);
  }
  __syncthreads();
  for (int i = threadIdx.x; i < NPG; i += 1024) {
    if (so[i]) atomicAdd(&dego[gb + i], so[i]);
    if (si[i]) atomicAdd(&degi[gb + i], si[i]);
  }
}

__global__ void k_scales(const int* __restrict__ dego, const int* __restrict__ degi,
                         float* __restrict__ rso, float* __restrict__ rsi) {
  int i = blockIdx.x * blockDim.x + threadIdx.x;
  if (i < NTOT) {
    int a = dego[i] > 1 ? dego[i] : 1;
    int b = degi[i] > 1 ? degi[i] : 1;
    rso[i] = rsqrtf((float)a);
    rsi[i] = rsqrtf((float)b);
  }
}

// ------------------------------------------------- prefold: x1 = features * rs_out
// Removes the dependent rs[s] load from the gather loop entirely.
__global__ void k_prefold(const float* __restrict__ features,
                          const int* __restrict__ dego, float* __restrict__ x1) {
  int t = blockIdx.x * blockDim.x + threadIdx.x;   // NTOT*16 threads
  int node = t >> 4, q = t & 15;
  int dg = dego[node];
  float sc = rsqrtf((float)(dg > 1 ? dg : 1));
  float4 v = *(const float4*)&features[(size_t)node * FIN + q * 4];
  v.x *= sc; v.y *= sc; v.z *= sc; v.w *= sc;
  *(float4*)&x1[(size_t)node * FIN + q * 4] = v;
}

// ------------------------------------------------- LDS-accumulated scatter
// grid (NB, 4 dim-slices, 2 edge-halves). 8-deep manual unroll: 16 edge-index
// loads + 8 gathers in flight per wave -> latency-limited chain amortized 8x.
// Output goes to half-specific buffer; consumers fold the a+b sum.
__global__ __launch_bounds__(1024) void k_agg(
    const int* __restrict__ src, const int* __restrict__ dst,
    const float* __restrict__ x, float* __restrict__ out) {
  __shared__ float acc[NPG * 16];
  const int g = blockIdx.x;
  const int d0 = blockIdx.y * 16;
  const int h = blockIdx.z;
  for (int i = threadIdx.x; i < NPG * 4; i += 1024)
    ((float4*)acc)[i] = make_float4(0.f, 0.f, 0.f, 0.f);
  __syncthreads();
  const int dim  = threadIdx.x & 15;
  const int slot = threadIdx.x >> 4;     // 64 edge slots
  const int gb = g * NPG;
  const int* sp = src + g * EPG + h * (EPG / 2) + slot;
  const int* dp = dst + g * EPG + h * (EPG / 2) + slot;
  const float* xp = x + d0 + dim;
  // 8192 edges / 64 slots = 128 per thread, groups of 8
  for (int e0 = 0; e0 < EPG / 2; e0 += 512) {
    int s[8], d[8];
#pragma unroll
    for (int j = 0; j < 8; ++j) {
      s[j] = sp[e0 + j * 64];
      d[j] = dp[e0 + j * 64];
    }
    float v[8];
#pragma unroll
    for (int j = 0; j < 8; ++j) v[j] = xp[(size_t)s[j] * FIN];
#pragma unroll
    for (int j = 0; j < 8; ++j) atomicAdd(&acc[(d[j] - gb) * 16 + dim], v[j]);
  }
  __syncthreads();
  float* o = out + (size_t)h * NTOT * FIN;
  for (int i = threadIdx.x; i < NPG * 4; i += 1024) {
    int node = i >> 2, dq = i & 3;
    *(float4*)&o[(size_t)(gb + node) * FIN + d0 + dq * 4] =
        *(float4*)&acc[node * 16 + dq * 4];
  }
}

// ------------------------------------------------- GEMM1: h = relu(((m1a+m1b)*rs_in)@W1 + b1) * rs_out
__global__ __launch_bounds__(256) void k_gemm1(
    const float* __restrict__ m1a, const float* __restrict__ m1b,
    const float* __restrict__ rsi, const float* __restrict__ rso,
    const float* __restrict__ W1, const float* __restrict__ b1,
    float* __restrict__ h) {
  __shared__ float sA[FIN][64];          // [k][node], 16 KB
  __shared__ float sW[FIN * FHID];       // [k][j],    32 KB
  __shared__ float sB[FHID];
  const int t = threadIdx.x;
  const int node0 = blockIdx.x * 64;
  for (int f = t; f < FIN * FHID / 4; f += 256)
    ((float4*)sW)[f] = ((const float4*)W1)[f];
  if (t < FHID) sB[t] = b1[t];
  for (int f = t; f < 64 * (FIN / 4); f += 256) {
    int node = f & 63, kq = f >> 6;
    float sc = rsi[node0 + node];
    size_t idx = (size_t)(node0 + node) * FIN + kq * 4;
    float4 va = *(const float4*)&m1a[idx];
    float4 vb = *(const float4*)&m1b[idx];
    sA[kq * 4 + 0][node] = (va.x + vb.x) * sc;
    sA[kq * 4 + 1][node] = (va.y + vb.y) * sc;
    sA[kq * 4 + 2][node] = (va.z + vb.z) * sc;
    sA[kq * 4 + 3][node] = (va.w + vb.w) * sc;
  }
  __syncthreads();
  const int tx = t & 15, ty = t >> 4;    // j0 = tx*8, n0 = ty*4
  float acc[4][8];
#pragma unroll
  for (int r = 0; r < 4; ++r)
#pragma unroll
    for (int c = 0; c < 8; ++c) acc[r][c] = 0.0f;
#pragma unroll 4
  for (int k = 0; k < FIN; ++k) {
    float4 a  = *(float4*)&sA[k][ty * 4];
    float4 w0 = *(float4*)&sW[k * FHID + tx * 8];
    float4 w1 = *(float4*)&sW[k * FHID + tx * 8 + 4];
    float av[4] = {a.x, a.y, a.z, a.w};
    float wv[8] = {w0.x, w0.y, w0.z, w0.w, w1.x, w1.y, w1.z, w1.w};
#pragma unroll
    for (int r = 0; r < 4; ++r)
#pragma unroll
      for (int c = 0; c < 8; ++c) acc[r][c] = fmaf(av[r], wv[c], acc[r][c]);
  }
#pragma unroll
  for (int r = 0; r < 4; ++r) {
    int node = node0 + ty * 4 + r;
    float sc = rso[node];
    float4 o0, o1;
    o0.x = fmaxf(acc[r][0] + sB[tx * 8 + 0], 0.f) * sc;
    o0.y = fmaxf(acc[r][1] + sB[tx * 8 + 1], 0.f) * sc;
    o0.z = fmaxf(acc[r][2] + sB[tx * 8 + 2], 0.f) * sc;
    o0.w = fmaxf(acc[r][3] + sB[tx * 8 + 3], 0.f) * sc;
    o1.x = fmaxf(acc[r][4] + sB[tx * 8 + 4], 0.f) * sc;
    o1.y = fmaxf(acc[r][5] + sB[tx * 8 + 5], 0.f) * sc;
    o1.z = fmaxf(acc[r][6] + sB[tx * 8 + 6], 0.f) * sc;
    o1.w = fmaxf(acc[r][7] + sB[tx * 8 + 7], 0.f) * sc;
    *(float4*)&h[(size_t)node * FHID + tx * 8]     = o0;
    *(float4*)&h[(size_t)node * FHID + tx * 8 + 4] = o1;
  }
}

// ------------------------------------------------- GEMM2: p = h @ [W2 | W3]
__global__ __launch_bounds__(256) void k_gemm2(
    const float* __restrict__ h, const float* __restrict__ W2,
    const float* __restrict__ W3, float* __restrict__ p) {
  __shared__ float sA[FHID][64];         // [k][node], 32 KB
  __shared__ float sW[FHID * 64];        // [k][j], j<32 -> W2, else W3, 32 KB
  const int t = threadIdx.x;
  const int node0 = blockIdx.x * 64;
  for (int f = t; f < FHID * FOUT / 4; f += 256) {
    int k = f >> 3, jq = f & 7;
    *(float4*)&sW[k * 64 + jq * 4]      = *(const float4*)&W2[k * FOUT + jq * 4];
  }
  for (int f = t; f < FHID * FOUT / 4; f += 256) {
    int k = f >> 3, jq = f & 7;
    *(float4*)&sW[k * 64 + 32 + jq * 4] = *(const float4*)&W3[k * FOUT + jq * 4];
  }
  for (int f = t; f < 64 * (FHID / 4); f += 256) {
    int node = f & 63, kq = f >> 6;
    float4 v = *(const float4*)&h[(size_t)(node0 + node) * FHID + kq * 4];
    sA[kq * 4 + 0][node] = v.x;
    sA[kq * 4 + 1][node] = v.y;
    sA[kq * 4 + 2][node] = v.z;
    sA[kq * 4 + 3][node] = v.w;
  }
  __syncthreads();
  const int tx = t & 15, ty = t >> 4;    // j0 = tx*4, n0 = ty*4
  float acc[4][4];
#pragma unroll
  for (int r = 0; r < 4; ++r)
#pragma unroll
    for (int c = 0; c < 4; ++c) acc[r][c] = 0.0f;
#pragma unroll 4
  for (int k = 0; k < FHID; ++k) {
    float4 a = *(float4*)&sA[k][ty * 4];
    float4 w = *(float4*)&sW[k * 64 + tx * 4];
    float av[4] = {a.x, a.y, a.z, a.w};
    float wv[4] = {w.x, w.y, w.z, w.w};
#pragma unroll
    for (int r = 0; r < 4; ++r)
#pragma unroll
      for (int c = 0; c < 4; ++c) acc[r][c] = fmaf(av[r], wv[c], acc[r][c]);
  }
#pragma unroll
  for (int r = 0; r < 4; ++r) {
    float4 o = {acc[r][0], acc[r][1], acc[r][2], acc[r][3]};
    *(float4*)&p[(size_t)(node0 + ty * 4 + r) * 64 + tx * 4] = o;
  }
}

// ------------------------------------------------- epilogue: mean / log_std
__global__ void k_epi(const float* __restrict__ m2a, const float* __restrict__ m2b,
                      const float* __restrict__ rsi,
                      const float* __restrict__ b2, const float* __restrict__ b3,
                      float* __restrict__ mean_, float* __restrict__ logstd_) {
  int t = blockIdx.x * blockDim.x + threadIdx.x;   // NTOT*8 threads
  int node = t >> 3, q = t & 7;
  float ri = rsi[node];
  size_t im = (size_t)node * 64 + q * 4;
  size_t il = im + 32;
  float4 ma = *(const float4*)&m2a[im];
  float4 mb = *(const float4*)&m2b[im];
  float4 la = *(const float4*)&m2a[il];
  float4 lb = *(const float4*)&m2b[il];
  float4 bb2 = *(const float4*)&b2[q * 4];
  float4 bb3 = *(const float4*)&b3[q * 4];
  float4 me = {(ma.x + mb.x) * ri + bb2.x, (ma.y + mb.y) * ri + bb2.y,
               (ma.z + mb.z) * ri + bb2.z, (ma.w + mb.w) * ri + bb2.w};
  float4 ls = {(la.x + lb.x) * ri + bb3.x, (la.y + lb.y) * ri + bb3.y,
               (la.z + lb.z) * ri + bb3.z, (la.w + lb.w) * ri + bb3.w};
  *(float4*)&mean_[(size_t)node * FOUT + q * 4]   = me;
  *(float4*)&logstd_[(size_t)node * FOUT + q * 4] = ls;
}

// ------------------------------------------------- adj = sigmoid(z z^T) per graph
__global__ __launch_bounds__(256) void k_adj(
    const float* __restrict__ mean_, const float* __restrict__ logstd_,
    const float* __restrict__ noise, float* __restrict__ adj) {
  __shared__ float sR[FOUT][128];
  __shared__ float sC[FOUT][128];
  const int g  = blockIdx.z;
  const int c0 = blockIdx.x * 128;
  const int r0 = blockIdx.y * 128;
  const int t  = threadIdx.x;
  const size_t gb = (size_t)g * NPG;
  for (int f = t; f < 2048; f += 256) {
    int half = f >> 10;
    int ff   = f & 1023;
    int node = ff & 127, kq = ff >> 7;
    int base = half ? c0 : r0;
    size_t idx = (gb + base + node) * FOUT + kq * 4;
    float4 m  = *(const float4*)&mean_[idx];
    float4 l  = *(const float4*)&logstd_[idx];
    float4 nz = *(const float4*)&noise[idx];
    float* s = half ? &sC[0][0] : &sR[0][0];
    s[(kq * 4 + 0) * 128 + node] = m.x + nz.x * __expf(l.x);
    s[(kq * 4 + 1) * 128 + node] = m.y + nz.y * __expf(l.y);
    s[(kq * 4 + 2) * 128 + node] = m.z + nz.z * __expf(l.z);
    s[(kq * 4 + 3) * 128 + node] = m.w + nz.w * __expf(l.w);
  }
  __syncthreads();
  const int tx = t & 15, ty = t >> 4;
  float acc[8][8];
#pragma unroll
  for (int r = 0; r < 8; ++r)
#pragma unroll
    for (int c = 0; c < 8; ++c) acc[r][c] = 0.0f;
#pragma unroll 2
  for (int k = 0; k < FOUT; ++k) {
    float ar[8], ac[8];
    *(float4*)&ar[0] = *(float4*)&sR[k][ty * 8];
    *(float4*)&ar[4] = *(float4*)&sR[k][ty * 8 + 4];
    *(float4*)&ac[0] = *(float4*)&sC[k][tx * 8];
    *(float4*)&ac[4] = *(float4*)&sC[k][tx * 8 + 4];
#pragma unroll
    for (int r = 0; r < 8; ++r)
#pragma unroll
      for (int c = 0; c < 8; ++c) acc[r][c] = fmaf(ar[r], ac[c], acc[r][c]);
  }
#pragma unroll
  for (int r = 0; r < 8; ++r) {
    size_t o = (gb + r0 + ty * 8 + r) * (size_t)NPG + c0 + tx * 8;
    float4 s0, s1;
    s0.x = 1.0f / (1.0f + __expf(-acc[r][0]));
    s0.y = 1.0f / (1.0f + __expf(-acc[r][1]));
    s0.z = 1.0f / (1.0f + __expf(-acc[r][2]));
    s0.w = 1.0f / (1.0f + __expf(-acc[r][3]));
    s1.x = 1.0f / (1.0f + __expf(-acc[r][4]));
    s1.y = 1.0f / (1.0f + __expf(-acc[r][5]));
    s1.z = 1.0f / (1.0f + __expf(-acc[r][6]));
    s1.w = 1.0f / (1.0f + __expf(-acc[r][7]));
    *(float4*)&adj[o]     = s0;
    *(float4*)&adj[o + 4] = s1;
  }
}

extern "C" void kernel_launch(void* const* d_in, const int* in_sizes, int n_in,
                              void* d_out, int out_size, void* d_ws, size_t ws_size,
                              hipStream_t stream) {
  const float* features = (const float*)d_in[0];
  const int*   src      = (const int*)d_in[1];
  const int*   dst      = (const int*)d_in[2];
  const float* noise    = (const float*)d_in[3];
  const float* W1       = (const float*)d_in[4];
  const float* b1       = (const float*)d_in[5];
  const float* W2       = (const float*)d_in[6];
  const float* b2       = (const float*)d_in[7];
  const float* W3       = (const float*)d_in[8];
  const float* b3       = (const float*)d_in[9];

  float* adj     = (float*)d_out;                              // 64*1024*1024
  float* mean_   = adj + (size_t)NB * NPG * NPG;               // N*32
  float* logstd_ = mean_ + (size_t)NTOT * FOUT;                // N*32

  // Scratch inside the adj region (written only by the final kernel, which
  // reads nothing from it). ~135 MB of 268 MB used.
  int*   dego = (int*)adj;                        // N ints
  int*   degi = dego + NTOT;                      // N ints
  float* rso  = (float*)(degi + NTOT);            // N
  float* rsi  = rso + NTOT;                       // N
  float* x1   = rsi + NTOT;                       // N*64  (features * rs_out)
  float* m1   = x1 + (size_t)NTOT * FIN;          // 2 * N*64 (halves)
  float* h    = m1 + (size_t)2 * NTOT * FIN;      // N*128
  float* p    = h + (size_t)NTOT * FHID;          // N*64
  float* m2   = p + (size_t)NTOT * FIN;           // 2 * N*64 (halves)
  float* m1b  = m1 + (size_t)NTOT * FIN;
  float* m2b  = m2 + (size_t)NTOT * FIN;

  hipMemsetAsync(dego, 0, (size_t)2 * NTOT * sizeof(int), stream);
  k_deg<<<dim3(NB, 4), 1024, 0, stream>>>(src, dst, dego, degi);
  k_scales<<<NTOT / 256, 256, 0, stream>>>(dego, degi, rso, rsi);
  k_prefold<<<NTOT * 16 / 256, 256, 0, stream>>>(features, dego, x1);
  // layer 1 aggregate: m1{a,b} = Agg_half(x1)
  k_agg<<<dim3(NB, FIN / 16, 2), 1024, 0, stream>>>(src, dst, x1, m1);
  // h = relu(((m1a+m1b) * rs_in) @ W1 + b1) * rs_out
  k_gemm1<<<NTOT / 64, 256, 0, stream>>>(m1, m1b, rsi, rso, W1, b1, h);
  // p = h @ [W2 | W3]  (project BEFORE aggregating: halves scatter traffic)
  k_gemm2<<<NTOT / 64, 256, 0, stream>>>(h, W2, W3, p);
  // layer 2 aggregate: m2{a,b} = Agg_half(p)
  k_agg<<<dim3(NB, FIN / 16, 2), 1024, 0, stream>>>(src, dst, p, m2);
  k_epi<<<NTOT * 8 / 256, 256, 0, stream>>>(m2, m2b, rsi, b2, b3, mean_, logstd_);
  k_adj<<<dim3(NPG / 128, NPG / 128, NB), 256, 0, stream>>>(mean_, logstd_, noise, adj);
}